// Round 18
// baseline (126.299 us; speedup 1.0000x reference)
//
#include <hip/hip_runtime.h>
#include <hip/hip_bf16.h>

#define SEQ 8192
#define HD 128
#define BM 256
#define BN 64
#define NQT (SEQ / BM)   // 32
#define THREADS 768

typedef __bf16 bf16_t;
typedef __bf16 bf16x2 __attribute__((ext_vector_type(2)));
typedef __bf16 bf16x8 __attribute__((ext_vector_type(8)));
typedef float f32x4 __attribute__((ext_vector_type(4)));
typedef float f32x16 __attribute__((ext_vector_type(16)));
typedef unsigned int u32x4 __attribute__((ext_vector_type(4)));

#if __has_builtin(__builtin_amdgcn_exp2f)
__device__ inline float exp2_fast(float x) { return __builtin_amdgcn_exp2f(x); }
#else
__device__ inline float exp2_fast(float x) { return exp2f(x); }
#endif

// v_permlane32_swap_b32: a.hi32lanes <-> b.lo32lanes (mapping verified R9).
__device__ inline void permswap32(unsigned int& a, unsigned int& b) {
#if __has_builtin(__builtin_amdgcn_permlane32_swap)
  auto r = __builtin_amdgcn_permlane32_swap(a, b, false, false);
  a = (unsigned int)r[0];
  b = (unsigned int)r[1];
#else
  asm volatile("v_permlane32_swap_b32 %0, %1" : "+v"(a), "+v"(b));
#endif
}

// async global->LDS DMA, 16 B per lane; lds dest wave-uniform, HW adds lane*16
__device__ inline void load_lds16(const void* g, void* l) {
  __builtin_amdgcn_global_load_lds(
      (const __attribute__((address_space(1))) void*)g,
      (__attribute__((address_space(3))) void*)l, 16, 0, 0);
}

// Hand-rolled __syncthreads (s_barrier counts waves; safe in wave-uniform
// divergent branches as long as every wave executes the same count).
#define SYNC()                                                             \
  do {                                                                     \
    asm volatile("s_waitcnt vmcnt(0) lgkmcnt(0)\n\ts_barrier" ::: "memory"); \
    __builtin_amdgcn_sched_barrier(0);                                     \
  } while (0)

// ---------------- prep ----------------
// Kb blocked: [tile T][d-chunk c 0..15][key r 0..63][8]  = K[T*64+r][c*8+j]
// VT blocked: [tile T][key-chunk kc 0..7][d 0..127][8]   = V[T*64+kc*8+j][d]
__global__ __launch_bounds__(256) void prep_kernel(const float* __restrict__ K,
                                                   const float* __restrict__ V,
                                                   bf16_t* __restrict__ Kb,
                                                   bf16_t* __restrict__ VT) {
  const int b = (int)blockIdx.x;
  const int tid = (int)threadIdx.x;
  if (b < 256) {
    // V tile: 64 keys x 64 d, staged f32 in LDS (coalesced reads)
    __shared__ float tile[64][65];
    const int T = b & 127;
    const int d0 = (b >> 7) * 64;
    const int s0 = T * 64;
    const int r = tid >> 2;          // 0..63 (key)
    const int c0 = (tid & 3) * 16;   // d offset
#pragma unroll
    for (int j4 = 0; j4 < 4; ++j4) {
      float4 x = *(const float4*)&V[(size_t)(s0 + r) * HD + d0 + c0 + j4 * 4];
      tile[r][c0 + j4 * 4 + 0] = x.x;
      tile[r][c0 + j4 * 4 + 1] = x.y;
      tile[r][c0 + j4 * 4 + 2] = x.z;
      tile[r][c0 + j4 * 4 + 3] = x.w;
    }
    __syncthreads();
    const int d_l = tid & 63;
    const int kc0 = (tid >> 6) * 2;  // 0,2,4,6
#pragma unroll
    for (int k2 = 0; k2 < 2; ++k2) {
      const int kc = kc0 + k2;
      bf16x8 wv;
#pragma unroll
      for (int j = 0; j < 8; ++j) wv[j] = (bf16_t)tile[kc * 8 + j][d_l];
      *(bf16x8*)&VT[((size_t)(T * 8 + kc) * 128 + d0 + d_l) * 8] = wv;
    }
  } else {
    // K convert: one 16B chunk per thread
    const int base = (b - 256) * 2048 + tid * 8;   // flat over 8192*128
    const int row = base >> 7;
    const int c = (base >> 3) & 15;
    const int T = row >> 6;
    const int r = row & 63;
    float4 a = *(const float4*)&K[base];
    float4 cc = *(const float4*)&K[base + 4];
    bf16x8 f;
    f[0] = (bf16_t)a.x; f[1] = (bf16_t)a.y; f[2] = (bf16_t)a.z; f[3] = (bf16_t)a.w;
    f[4] = (bf16_t)cc.x; f[5] = (bf16_t)cc.y; f[6] = (bf16_t)cc.z; f[7] = (bf16_t)cc.w;
    *(bf16x8*)&Kb[((size_t)(T * 16 + c) * 64 + r) * 8] = f;
  }
}

// ---------------- main flash-attention kernel ----------------
// R18 = R17 wave-specialization + LDS-instruction reduction (the measured
// bottleneck: ~67% LDS-pipe busy at R17). 12 waves (768 thr), 1 block/CU,
// 3 waves/SIMD (launch_bounds(768,3) -> ~170 reg cap):
//   waves 0-3  (QK role): each owns TWO q-groups (g0=2w, g1=2w+1). Each
//     K-fragment pair is read ONCE and feeds 4 MFMA chains (both groups)
//     -> K-reads/CU-iter 128 -> 64. Live: qf[2][8](64) + 4 sacc(64) ~150.
//   waves 4-11 (PV role): p=w-4 owns q-groups (p&3)*2, (p&3)*2+1 and
//     d-half p>>2. o_acc[2][2](64). Per iter 8 P + 8 V reads for 16 MFMA
//     (was 4+16 for 16) -> PV reads 160 -> 128.
// Total b128/CU-iter: 320 -> 224. Barrier counts identical across roles
// (nit+1 each). LDS: K 2x16K + V 2x16K + P 2x32K = 128 KB.
__global__ __launch_bounds__(THREADS, 3) void fattn_kernel(
    const float* __restrict__ Q, const bf16_t* __restrict__ Kb,
    const bf16_t* __restrict__ VT, float* __restrict__ Opart,
    float* __restrict__ Lpart, int kshift, int nit) {
  __shared__ __align__(16) bf16_t kt2[2][16][64][8];   // 32 KB [buf][d-chunk][key][8]
  __shared__ __align__(16) bf16_t vt2[2][8][128][8];   // 32 KB [buf][key-chunk][d][8]
  __shared__ __align__(16) char pbuf[2][8][4][64][16]; // 64 KB [buf][qg][chunk][lane][16B]

  const int tid = (int)threadIdx.x;
  const int lane = tid & 63;
  const int w = tid >> 6;          // 0..11
  const int h = lane >> 5;
  const int n32 = lane & 31;

  const int qt = (int)blockIdx.x >> kshift;
  const int sp = (int)blockIdx.x & ((1 << kshift) - 1);
  const int qbase = qt * BM;
  const int tile0 = sp * nit;          // first 64-key tile index

  const float SC2 = 0.08838834764831845f * 1.4426950408889634f; // (1/sqrt(128))*log2e

  char* const ktB = (char*)&kt2[0][0][0][0];
  char* const vtB = (char*)&vt2[0][0][0][0];
  char* const pbB = (char*)&pbuf[0][0][0][0][0];

// QK waves (w 0..3): 4 K regions each -> rr 0..15.
#define DMA_K(TILE, BUF)                                                   \
  _Pragma("unroll")                                                        \
  for (int t = 0; t < 4; ++t) {                                            \
    const int rr = w * 4 + t;                                              \
    load_lds16(Kb + ((size_t)((TILE) * 16 + rr) * 64 + lane) * 8,          \
               ktB + (BUF) * 16384 + rr * 1024);                           \
  }
// PV waves (w 4..11): 2 V regions each -> rr 0..15.
#define DMA_V(TILE, BUF)                                                   \
  _Pragma("unroll")                                                        \
  for (int t = 0; t < 2; ++t) {                                            \
    const int rr = (w - 4) * 2 + t;                                        \
    load_lds16(VT + ((size_t)((TILE) * 8 + (rr >> 1)) * 128 + (rr & 1) * 64 + lane) * 8, \
               vtB + (BUF) * 16384 + rr * 1024);                           \
  }

// exp -> pack -> permlane32_swap -> P A-frag (16 keys) -> pbuf write.
// pbuf per-buffer stride 32768 B, per-qg 4096 B, per-chunk 1024 B.
#define EXPPACKW(SACC, KK2, QG, CIDX, BUF, LACC)                           \
  {                                                                        \
    float pf[8];                                                           \
    _Pragma("unroll")                                                      \
    for (int j = 0; j < 8; ++j) pf[j] = exp2_fast((SACC)[8 * (KK2) + j]);  \
    LACC += ((pf[0] + pf[1]) + (pf[2] + pf[3])) +                          \
            ((pf[4] + pf[5]) + (pf[6] + pf[7]));                           \
    bf16x2 p0, p1, p2, p3;                                                 \
    p0[0] = (bf16_t)pf[0]; p0[1] = (bf16_t)pf[1];                          \
    p1[0] = (bf16_t)pf[2]; p1[1] = (bf16_t)pf[3];                          \
    p2[0] = (bf16_t)pf[4]; p2[1] = (bf16_t)pf[5];                          \
    p3[0] = (bf16_t)pf[6]; p3[1] = (bf16_t)pf[7];                          \
    unsigned int sA = __builtin_bit_cast(unsigned int, p0);                \
    unsigned int sB = __builtin_bit_cast(unsigned int, p1);                \
    unsigned int sC = __builtin_bit_cast(unsigned int, p2);                \
    unsigned int sD = __builtin_bit_cast(unsigned int, p3);                \
    permswap32(sA, sC);                                                    \
    permswap32(sB, sD);                                                    \
    u32x4 fv;                                                              \
    fv[0] = sA; fv[1] = sB; fv[2] = sC; fv[3] = sD;                        \
    *(u32x4*)(pbB + (BUF) * 32768 + (QG) * 4096 + (CIDX) * 1024 + lane * 16) = fv; \
  }

// QK body (CUR = IT&1 literal): DMA K(IT+1); QK^T for BOTH q-groups with
// single af reads (4 chains); exp -> pbuf[CUR]; barrier.
#define QKBODY(IT, CUR)                                                    \
  {                                                                        \
    const int it_ = (IT);                                                  \
    if (it_ + 1 < nit) { DMA_K(tile0 + it_ + 1, (CUR) ^ 1) }               \
    f32x16 s00, s10, s01, s11;   /* s<keyhalf><qgroup> */                  \
    _Pragma("unroll")                                                      \
    for (int e = 0; e < 16; ++e) { s00[e] = 0.f; s10[e] = 0.f; s01[e] = 0.f; s11[e] = 0.f; } \
    _Pragma("unroll")                                                      \
    for (int kk = 0; kk < 8; ++kk) {                                       \
      bf16x8 af0 = *(const bf16x8*)(ktB + (CUR) * 16384 + (2 * kk + h) * 1024 + n32 * 16); \
      bf16x8 af1 = *(const bf16x8*)(ktB + (CUR) * 16384 + (2 * kk + h) * 1024 + (32 + n32) * 16); \
      s00 = __builtin_amdgcn_mfma_f32_32x32x16_bf16(af0, qf[0][kk], s00, 0, 0, 0); \
      s10 = __builtin_amdgcn_mfma_f32_32x32x16_bf16(af1, qf[0][kk], s10, 0, 0, 0); \
      s01 = __builtin_amdgcn_mfma_f32_32x32x16_bf16(af0, qf[1][kk], s01, 0, 0, 0); \
      s11 = __builtin_amdgcn_mfma_f32_32x32x16_bf16(af1, qf[1][kk], s11, 0, 0, 0); \
    }                                                                      \
    EXPPACKW(s00, 0, g0, 0, CUR, l_acc0) EXPPACKW(s00, 1, g0, 1, CUR, l_acc0) \
    EXPPACKW(s10, 0, g0, 2, CUR, l_acc0) EXPPACKW(s10, 1, g0, 3, CUR, l_acc0) \
    EXPPACKW(s01, 0, g1, 0, CUR, l_acc1) EXPPACKW(s01, 1, g1, 1, CUR, l_acc1) \
    EXPPACKW(s11, 0, g1, 2, CUR, l_acc1) EXPPACKW(s11, 1, g1, 3, CUR, l_acc1) \
    SYNC();                                                                \
  }

// PV compute for buffer PBUF: O(2 q-groups x 64-d-half) += P x V.
// Per C: 2 P reads + 2 V reads -> 4 MFMA.
#define PVCOMP(PBUF)                                                       \
  _Pragma("unroll")                                                        \
  for (int C = 0; C < 4; ++C) {                                            \
    bf16x8 pa0 = *(const bf16x8*)(pbB + (PBUF) * 32768 + g0 * 4096 + C * 1024 + lane * 16); \
    bf16x8 pa1 = *(const bf16x8*)(pbB + (PBUF) * 32768 + g1 * 4096 + C * 1024 + lane * 16); \
    bf16x8 vb0 = *(const bf16x8*)(vtB + (PBUF) * 16384 + (C * 2 + h) * 2048 + \
                                  (dh * 64 + n32) * 16);                   \
    bf16x8 vb1 = *(const bf16x8*)(vtB + (PBUF) * 16384 + (C * 2 + h) * 2048 + \
                                  (dh * 64 + 32 + n32) * 16);              \
    o_acc00 = __builtin_amdgcn_mfma_f32_32x32x16_bf16(pa0, vb0, o_acc00, 0, 0, 0); \
    o_acc01 = __builtin_amdgcn_mfma_f32_32x32x16_bf16(pa0, vb1, o_acc01, 0, 0, 0); \
    o_acc10 = __builtin_amdgcn_mfma_f32_32x32x16_bf16(pa1, vb0, o_acc10, 0, 0, 0); \
    o_acc11 = __builtin_amdgcn_mfma_f32_32x32x16_bf16(pa1, vb1, o_acc11, 0, 0, 0); \
  }

// PV body for iteration IT>=1 (CUR = IT&1): DMA V(IT); PV(IT-1); barrier.
#define PVBODY(IT, CUR)                                                    \
  {                                                                        \
    DMA_V(tile0 + (IT), CUR)                                               \
    PVCOMP((CUR) ^ 1)                                                      \
    SYNC();                                                                \
  }

  if (w < 4) {
    // ================= QK producer role (2 q-groups) =================
    const int g0 = 2 * w, g1 = 2 * w + 1;
    bf16x8 qf[2][8];
#pragma unroll
    for (int j = 0; j < 2; ++j) {
      const float* qp = Q + (size_t)(qbase + (2 * w + j) * 32 + n32) * HD + h * 8;
#pragma unroll
      for (int kk = 0; kk < 8; ++kk) {
        float4 a = *(const float4*)(qp + kk * 16);
        float4 b = *(const float4*)(qp + kk * 16 + 4);
        bf16x8 f;
        f[0] = (bf16_t)(a.x * SC2); f[1] = (bf16_t)(a.y * SC2);
        f[2] = (bf16_t)(a.z * SC2); f[3] = (bf16_t)(a.w * SC2);
        f[4] = (bf16_t)(b.x * SC2); f[5] = (bf16_t)(b.y * SC2);
        f[6] = (bf16_t)(b.z * SC2); f[7] = (bf16_t)(b.w * SC2);
        qf[j][kk] = f;
      }
    }
    float l_acc0 = 0.f, l_acc1 = 0.f;

    DMA_K(tile0, 0)
    SYNC();   // prologue barrier (PV side matches)

    for (int it = 0; it < nit; it += 2) {   // nit even
      QKBODY(it, 0)
      QKBODY(it + 1, 1)
    }

    // epilogue: L for both q-groups (this wave covered all 64 keys)
    float l0 = l_acc0 + __shfl_xor(l_acc0, 32);
    float l1 = l_acc1 + __shfl_xor(l_acc1, 32);
    if (lane < 32) {
      Lpart[(size_t)sp * SEQ + qbase + g0 * 32 + n32] = l0;
      Lpart[(size_t)sp * SEQ + qbase + g1 * 32 + n32] = l1;
    }
  } else {
    // ======== PV consumer role (2 q-groups x 64-d-half) ========
    const int p = w - 4;             // 0..7
    const int g0 = (p & 3) * 2, g1 = g0 + 1;
    const int dh = p >> 2;           // d-half 0/1
    f32x16 o_acc00, o_acc01, o_acc10, o_acc11;
#pragma unroll
    for (int e = 0; e < 16; ++e) {
      o_acc00[e] = 0.f; o_acc01[e] = 0.f; o_acc10[e] = 0.f; o_acc11[e] = 0.f;
    }

    SYNC();   // match prologue barrier

    // it = 0: stage V(0); no P yet
    DMA_V(tile0, 0)
    SYNC();
    // it = 1: stage V(1); PV(0)
    PVBODY(1, 1)
    // it = 2 .. nit-1 (count nit-2, even)
    for (int it = 2; it < nit; it += 2) {
      PVBODY(it, 0)
      PVBODY(it + 1, 1)
    }
    // tail: PV(nit-1); P in pbuf[1], V in vt[1] (nit even -> nit-1 odd)
    PVCOMP(1)

    // epilogue: O block store (2 groups x own 64-d half)
#pragma unroll
    for (int g = 0; g < 2; ++g) {
      float* op = Opart + ((size_t)sp * SEQ + qbase + (g0 + g) * 32) * HD + dh * 64;
      const f32x16& oa0 = g ? o_acc10 : o_acc00;
      const f32x16& oa1 = g ? o_acc11 : o_acc01;
#pragma unroll
      for (int reg = 0; reg < 16; ++reg) {
        const int row = (reg & 3) + 8 * (reg >> 2) + 4 * h;
        op[row * HD + n32] = oa0[reg];
        op[row * HD + 32 + n32] = oa1[reg];
      }
    }
  }

#undef QKBODY
#undef PVBODY
#undef PVCOMP
#undef EXPPACKW
#undef DMA_K
#undef DMA_V
}

// ---------------- combine: out = sum_s O_s / sum_s l_s ----------------
__global__ __launch_bounds__(256) void combine_kernel(const float* __restrict__ Opart,
                                                      const float* __restrict__ Lpart,
                                                      float* __restrict__ out, int ksplit) {
  const int tid = (int)threadIdx.x;
  const int row = (int)blockIdx.x * 8 + (tid >> 5);
  const int c0 = (tid & 31) * 4;
  float lsum = 0.f;
  for (int s = 0; s < ksplit; ++s) lsum += Lpart[(size_t)s * SEQ + row];
  f32x4 acc;
#pragma unroll
  for (int e = 0; e < 4; ++e) acc[e] = 0.f;
  for (int s = 0; s < ksplit; ++s) {
    f32x4 o = *(const f32x4*)&Opart[((size_t)s * SEQ + row) * HD + c0];
#pragma unroll
    for (int e = 0; e < 4; ++e) acc[e] += o[e];
  }
  const float inv = 1.0f / lsum;
  f32x4 res;
#pragma unroll
  for (int e = 0; e < 4; ++e) res[e] = acc[e] * inv;
  *(f32x4*)&out[(size_t)row * HD + c0] = res;
}

extern "C" void kernel_launch(void* const* d_in, const int* in_sizes, int n_in,
                              void* d_out, int out_size, void* d_ws, size_t ws_size,
                              hipStream_t stream) {
  const float* Q = (const float*)d_in[0];
  const float* K = (const float*)d_in[1];
  const float* V = (const float*)d_in[2];
  float* out = (float*)d_out;

  int ksplit = 8, kshift = 3;
  while (ksplit > 1) {
    size_t need = (size_t)ksplit * SEQ * HD * 4
                + (size_t)ksplit * SEQ * 4
                + (size_t)SEQ * HD * 2 * 2;
    if (need <= ws_size) break;
    ksplit >>= 1; kshift--;
  }

  char* ws = (char*)d_ws;
  float* Opart = (float*)ws;
  float* Lpart = (float*)(ws + (size_t)ksplit * SEQ * HD * 4);
  bf16_t* Kb = (bf16_t*)(ws + (size_t)ksplit * SEQ * HD * 4 + (size_t)ksplit * SEQ * 4);
  bf16_t* VT = Kb + (size_t)SEQ * HD;

  const int nit = SEQ / (ksplit * BN);

  prep_kernel<<<768, 256, 0, stream>>>(K, V, Kb, VT);
  fattn_kernel<<<NQT * ksplit, THREADS, 0, stream>>>(Q, Kb, VT, Opart, Lpart, kshift, nit);
  combine_kernel<<<SEQ / 8, 256, 0, stream>>>(Opart, Lpart, out, ksplit);
}

// Round 19
// 108.725 us; speedup vs baseline: 1.1616x; 1.1616x over previous
//
#include <hip/hip_runtime.h>
#include <hip/hip_bf16.h>

#define SEQ 8192
#define HD 128
#define BM 256
#define BN 64
#define NQT (SEQ / BM)   // 32
#define THREADS 1024

typedef __bf16 bf16_t;
typedef __bf16 bf16x2 __attribute__((ext_vector_type(2)));
typedef __bf16 bf16x8 __attribute__((ext_vector_type(8)));
typedef float f32x4 __attribute__((ext_vector_type(4)));
typedef float f32x16 __attribute__((ext_vector_type(16)));
typedef unsigned int u32x4 __attribute__((ext_vector_type(4)));

#if __has_builtin(__builtin_amdgcn_exp2f)
__device__ inline float exp2_fast(float x) { return __builtin_amdgcn_exp2f(x); }
#else
__device__ inline float exp2_fast(float x) { return exp2f(x); }
#endif

// v_permlane32_swap_b32: a.hi32lanes <-> b.lo32lanes (mapping verified R9).
__device__ inline void permswap32(unsigned int& a, unsigned int& b) {
#if __has_builtin(__builtin_amdgcn_permlane32_swap)
  auto r = __builtin_amdgcn_permlane32_swap(a, b, false, false);
  a = (unsigned int)r[0];
  b = (unsigned int)r[1];
#else
  asm volatile("v_permlane32_swap_b32 %0, %1" : "+v"(a), "+v"(b));
#endif
}

// async global->LDS DMA, 16 B per lane; lds dest wave-uniform, HW adds lane*16
__device__ inline void load_lds16(const void* g, void* l) {
  __builtin_amdgcn_global_load_lds(
      (const __attribute__((address_space(1))) void*)g,
      (__attribute__((address_space(3))) void*)l, 16, 0, 0);
}

// Hand-rolled __syncthreads (s_barrier counts waves; safe in wave-uniform
// divergent branches as long as every wave executes the same count).
#define SYNC()                                                             \
  do {                                                                     \
    asm volatile("s_waitcnt vmcnt(0) lgkmcnt(0)\n\ts_barrier" ::: "memory"); \
    __builtin_amdgcn_sched_barrier(0);                                     \
  } while (0)

// ---------------- prep ----------------
// Kb blocked: [tile T][d-chunk c 0..15][key r 0..63][8]  = K[T*64+r][c*8+j]
// VT blocked: [tile T][key-chunk kc 0..7][d 0..127][8]   = V[T*64+kc*8+j][d]
__global__ __launch_bounds__(256) void prep_kernel(const float* __restrict__ K,
                                                   const float* __restrict__ V,
                                                   bf16_t* __restrict__ Kb,
                                                   bf16_t* __restrict__ VT) {
  const int b = (int)blockIdx.x;
  const int tid = (int)threadIdx.x;
  if (b < 256) {
    // V tile: 64 keys x 64 d, staged f32 in LDS (coalesced reads)
    __shared__ float tile[64][65];
    const int T = b & 127;
    const int d0 = (b >> 7) * 64;
    const int s0 = T * 64;
    const int r = tid >> 2;          // 0..63 (key)
    const int c0 = (tid & 3) * 16;   // d offset
#pragma unroll
    for (int j4 = 0; j4 < 4; ++j4) {
      float4 x = *(const float4*)&V[(size_t)(s0 + r) * HD + d0 + c0 + j4 * 4];
      tile[r][c0 + j4 * 4 + 0] = x.x;
      tile[r][c0 + j4 * 4 + 1] = x.y;
      tile[r][c0 + j4 * 4 + 2] = x.z;
      tile[r][c0 + j4 * 4 + 3] = x.w;
    }
    __syncthreads();
    const int d_l = tid & 63;
    const int kc0 = (tid >> 6) * 2;  // 0,2,4,6
#pragma unroll
    for (int k2 = 0; k2 < 2; ++k2) {
      const int kc = kc0 + k2;
      bf16x8 wv;
#pragma unroll
      for (int j = 0; j < 8; ++j) wv[j] = (bf16_t)tile[kc * 8 + j][d_l];
      *(bf16x8*)&VT[((size_t)(T * 8 + kc) * 128 + d0 + d_l) * 8] = wv;
    }
  } else {
    // K convert: one 16B chunk per thread
    const int base = (b - 256) * 2048 + tid * 8;   // flat over 8192*128
    const int row = base >> 7;
    const int c = (base >> 3) & 15;
    const int T = row >> 6;
    const int r = row & 63;
    float4 a = *(const float4*)&K[base];
    float4 cc = *(const float4*)&K[base + 4];
    bf16x8 f;
    f[0] = (bf16_t)a.x; f[1] = (bf16_t)a.y; f[2] = (bf16_t)a.z; f[3] = (bf16_t)a.w;
    f[4] = (bf16_t)cc.x; f[5] = (bf16_t)cc.y; f[6] = (bf16_t)cc.z; f[7] = (bf16_t)cc.w;
    *(bf16x8*)&Kb[((size_t)(T * 16 + c) * 64 + r) * 8] = f;
  }
}

// ---------------- main flash-attention kernel ----------------
// R19 = R17 (balanced 8+8 wave specialization, VGPR 64, no spill) with ONE
// change: PV wave p owns 2 q-groups x one 64-d half (was 1 q-group x 128d).
// Per C-chunk: 2 P-reads + 2 V-reads -> 4 MFMA; per iter 16 reads for
// 16 MFMA (R17: 20 for 16 -- V was 4x redundant across q-groups, now 2x).
// Per-CU-iter b128 reads 288 -> 256 on the ~67%-busy LDS pipe. Registers
// (4x f32x16), MFMA counts, role balance, DMA, barrier counts identical.
// R18 lesson applied: roles must stay balanced (16 MFMA/wave/iter both).
__global__ __launch_bounds__(THREADS, 4) void fattn_kernel(
    const float* __restrict__ Q, const bf16_t* __restrict__ Kb,
    const bf16_t* __restrict__ VT, float* __restrict__ Opart,
    float* __restrict__ Lpart, int kshift, int nit) {
  __shared__ __align__(16) bf16_t kt2[2][16][64][8];   // 32 KB [buf][d-chunk][key][8]
  __shared__ __align__(16) bf16_t vt2[2][8][128][8];   // 32 KB [buf][key-chunk][d][8]
  __shared__ __align__(16) char pbuf[2][8][4][64][16]; // 64 KB [buf][qg][chunk][lane][16B]

  const int tid = (int)threadIdx.x;
  const int lane = tid & 63;
  const int w = tid >> 6;          // 0..15
  const int qw = w & 7;            // DMA region group / QK q-group
  const int h = lane >> 5;
  const int n32 = lane & 31;

  const int qt = (int)blockIdx.x >> kshift;
  const int sp = (int)blockIdx.x & ((1 << kshift) - 1);
  const int qbase = qt * BM;
  const int tile0 = sp * nit;          // first 64-key tile index

  const float SC2 = 0.08838834764831845f * 1.4426950408889634f; // (1/sqrt(128))*log2e

  char* const ktB = (char*)&kt2[0][0][0][0];
  char* const vtB = (char*)&vt2[0][0][0][0];
  char* const pbB = (char*)&pbuf[0][0][0][0][0];

#define DMA_K(TILE, BUF)                                                   \
  _Pragma("unroll")                                                        \
  for (int t = 0; t < 2; ++t) {                                            \
    const int rr = qw * 2 + t;                                             \
    load_lds16(Kb + ((size_t)((TILE) * 16 + rr) * 64 + lane) * 8,          \
               ktB + (BUF) * 16384 + rr * 1024);                           \
  }
#define DMA_V(TILE, BUF)                                                   \
  _Pragma("unroll")                                                        \
  for (int t = 0; t < 2; ++t) {                                            \
    const int rr = qw * 2 + t;                                             \
    load_lds16(VT + ((size_t)((TILE) * 8 + (rr >> 1)) * 128 + (rr & 1) * 64 + lane) * 8, \
               vtB + (BUF) * 16384 + rr * 1024);                           \
  }

// exp -> pack -> permlane32_swap -> P A-frag (16 keys) -> pbuf write.
// pbuf per-buffer stride 32768 B, per-qg 4096 B, per-chunk 1024 B.
#define EXPPACKW(SACC, KK2, CIDX, BUF)                                     \
  {                                                                        \
    float pf[8];                                                           \
    _Pragma("unroll")                                                      \
    for (int j = 0; j < 8; ++j) pf[j] = exp2_fast((SACC)[8 * (KK2) + j]);  \
    l_acc += ((pf[0] + pf[1]) + (pf[2] + pf[3])) +                         \
             ((pf[4] + pf[5]) + (pf[6] + pf[7]));                          \
    bf16x2 p0, p1, p2, p3;                                                 \
    p0[0] = (bf16_t)pf[0]; p0[1] = (bf16_t)pf[1];                          \
    p1[0] = (bf16_t)pf[2]; p1[1] = (bf16_t)pf[3];                          \
    p2[0] = (bf16_t)pf[4]; p2[1] = (bf16_t)pf[5];                          \
    p3[0] = (bf16_t)pf[6]; p3[1] = (bf16_t)pf[7];                          \
    unsigned int sA = __builtin_bit_cast(unsigned int, p0);                \
    unsigned int sB = __builtin_bit_cast(unsigned int, p1);                \
    unsigned int sC = __builtin_bit_cast(unsigned int, p2);                \
    unsigned int sD = __builtin_bit_cast(unsigned int, p3);                \
    permswap32(sA, sC);                                                    \
    permswap32(sB, sD);                                                    \
    u32x4 fv;                                                              \
    fv[0] = sA; fv[1] = sB; fv[2] = sC; fv[3] = sD;                        \
    *(u32x4*)(pbB + (BUF) * 32768 + qw * 4096 + (CIDX) * 1024 + lane * 16) = fv; \
  }

// QK body for iteration IT (CUR = IT&1 literal): DMA K(IT+1); QK^T from
// kt2[CUR] (interleaved chains); exp -> pbuf[CUR]; barrier.
#define QKBODY(IT, CUR)                                                    \
  {                                                                        \
    const int it_ = (IT);                                                  \
    if (it_ + 1 < nit) { DMA_K(tile0 + it_ + 1, (CUR) ^ 1) }               \
    f32x16 sacc0, sacc1;                                                   \
    _Pragma("unroll")                                                      \
    for (int e = 0; e < 16; ++e) { sacc0[e] = 0.f; sacc1[e] = 0.f; }       \
    _Pragma("unroll")                                                      \
    for (int kk = 0; kk < 8; ++kk) {                                       \
      bf16x8 af0 = *(const bf16x8*)(ktB + (CUR) * 16384 + (2 * kk + h) * 1024 + n32 * 16); \
      sacc0 = __builtin_amdgcn_mfma_f32_32x32x16_bf16(af0, qf[kk], sacc0, 0, 0, 0); \
      bf16x8 af1 = *(const bf16x8*)(ktB + (CUR) * 16384 + (2 * kk + h) * 1024 + (32 + n32) * 16); \
      sacc1 = __builtin_amdgcn_mfma_f32_32x32x16_bf16(af1, qf[kk], sacc1, 0, 0, 0); \
    }                                                                      \
    EXPPACKW(sacc0, 0, 0, CUR)                                             \
    EXPPACKW(sacc0, 1, 1, CUR)                                             \
    EXPPACKW(sacc1, 0, 2, CUR)                                             \
    EXPPACKW(sacc1, 1, 3, CUR)                                             \
    SYNC();                                                                \
  }

// PV compute for tile buffer PBUF: O(2 q-groups x own 64-d half) += P x V.
// Per C: 2 P-reads + 2 V-reads -> 4 MFMA (V shared across q-groups).
#define PVCOMP(PBUF)                                                       \
  _Pragma("unroll")                                                        \
  for (int C = 0; C < 4; ++C) {                                            \
    bf16x8 pa0 = *(const bf16x8*)(pbB + (PBUF) * 32768 + g0 * 4096 + C * 1024 + lane * 16); \
    bf16x8 pa1 = *(const bf16x8*)(pbB + (PBUF) * 32768 + g1 * 4096 + C * 1024 + lane * 16); \
    bf16x8 vb0 = *(const bf16x8*)(vtB + (PBUF) * 16384 + (C * 2 + h) * 2048 + \
                                  (dh * 64 + n32) * 16);                   \
    bf16x8 vb1 = *(const bf16x8*)(vtB + (PBUF) * 16384 + (C * 2 + h) * 2048 + \
                                  (dh * 64 + 32 + n32) * 16);              \
    o_acc00 = __builtin_amdgcn_mfma_f32_32x32x16_bf16(pa0, vb0, o_acc00, 0, 0, 0); \
    o_acc01 = __builtin_amdgcn_mfma_f32_32x32x16_bf16(pa0, vb1, o_acc01, 0, 0, 0); \
    o_acc10 = __builtin_amdgcn_mfma_f32_32x32x16_bf16(pa1, vb0, o_acc10, 0, 0, 0); \
    o_acc11 = __builtin_amdgcn_mfma_f32_32x32x16_bf16(pa1, vb1, o_acc11, 0, 0, 0); \
  }

// PV body for iteration IT>=1 (CUR = IT&1): DMA V(IT); PV(IT-1); barrier.
#define PVBODY(IT, CUR)                                                    \
  {                                                                        \
    DMA_V(tile0 + (IT), CUR)                                               \
    PVCOMP((CUR) ^ 1)                                                      \
    SYNC();                                                                \
  }

  if (w < 8) {
    // ================= QK producer role =================
    bf16x8 qf[8];
    {
      const float* qp = Q + (size_t)(qbase + qw * 32 + n32) * HD + h * 8;
#pragma unroll
      for (int kk = 0; kk < 8; ++kk) {
        float4 a = *(const float4*)(qp + kk * 16);
        float4 b = *(const float4*)(qp + kk * 16 + 4);
        bf16x8 f;
        f[0] = (bf16_t)(a.x * SC2); f[1] = (bf16_t)(a.y * SC2);
        f[2] = (bf16_t)(a.z * SC2); f[3] = (bf16_t)(a.w * SC2);
        f[4] = (bf16_t)(b.x * SC2); f[5] = (bf16_t)(b.y * SC2);
        f[6] = (bf16_t)(b.z * SC2); f[7] = (bf16_t)(b.w * SC2);
        qf[kk] = f;
      }
    }
    float l_acc = 0.f;

    DMA_K(tile0, 0)
    SYNC();   // prologue barrier (PV side matches)

    for (int it = 0; it < nit; it += 2) {   // nit even
      QKBODY(it, 0)
      QKBODY(it + 1, 1)
    }

    // epilogue: L (this wave covered all 64 keys of every tile)
    float l = l_acc + __shfl_xor(l_acc, 32);
    if (lane < 32)
      Lpart[(size_t)sp * SEQ + qbase + qw * 32 + n32] = l;
  } else {
    // ======== PV consumer role (2 q-groups x own 64-d half) ========
    const int p = w - 8;             // 0..7
    const int g0 = (p & 3) * 2, g1 = g0 + 1;
    const int dh = p >> 2;           // d-half 0/1
    f32x16 o_acc00, o_acc01, o_acc10, o_acc11;
#pragma unroll
    for (int e = 0; e < 16; ++e) {
      o_acc00[e] = 0.f; o_acc01[e] = 0.f; o_acc10[e] = 0.f; o_acc11[e] = 0.f;
    }

    SYNC();   // match prologue barrier

    // it = 0: stage V(0); no P yet
    DMA_V(tile0, 0)
    SYNC();
    // it = 1: stage V(1); PV(0)
    PVBODY(1, 1)
    // it = 2 .. nit-1 (count nit-2, even)
    for (int it = 2; it < nit; it += 2) {
      PVBODY(it, 0)
      PVBODY(it + 1, 1)
    }
    // tail: PV(nit-1); P in pbuf[1], V in vt[1] (nit even -> nit-1 odd)
    PVCOMP(1)

    // epilogue: O block store (2 groups x own 64-d half)
#pragma unroll
    for (int g = 0; g < 2; ++g) {
      float* op = Opart + ((size_t)sp * SEQ + qbase + (g0 + g) * 32) * HD + dh * 64;
      const f32x16& oa0 = g ? o_acc10 : o_acc00;
      const f32x16& oa1 = g ? o_acc11 : o_acc01;
#pragma unroll
      for (int reg = 0; reg < 16; ++reg) {
        const int row = (reg & 3) + 8 * (reg >> 2) + 4 * h;
        op[row * HD + n32] = oa0[reg];
        op[row * HD + 32 + n32] = oa1[reg];
      }
    }
  }

#undef QKBODY
#undef PVBODY
#undef PVCOMP
#undef EXPPACKW
#undef DMA_K
#undef DMA_V
}

// ---------------- combine: out = sum_s O_s / sum_s l_s ----------------
__global__ __launch_bounds__(256) void combine_kernel(const float* __restrict__ Opart,
                                                      const float* __restrict__ Lpart,
                                                      float* __restrict__ out, int ksplit) {
  const int tid = (int)threadIdx.x;
  const int row = (int)blockIdx.x * 8 + (tid >> 5);
  const int c0 = (tid & 31) * 4;
  float lsum = 0.f;
  for (int s = 0; s < ksplit; ++s) lsum += Lpart[(size_t)s * SEQ + row];
  f32x4 acc;
#pragma unroll
  for (int e = 0; e < 4; ++e) acc[e] = 0.f;
  for (int s = 0; s < ksplit; ++s) {
    f32x4 o = *(const f32x4*)&Opart[((size_t)s * SEQ + row) * HD + c0];
#pragma unroll
    for (int e = 0; e < 4; ++e) acc[e] += o[e];
  }
  const float inv = 1.0f / lsum;
  f32x4 res;
#pragma unroll
  for (int e = 0; e < 4; ++e) res[e] = acc[e] * inv;
  *(f32x4*)&out[(size_t)row * HD + c0] = res;
}

extern "C" void kernel_launch(void* const* d_in, const int* in_sizes, int n_in,
                              void* d_out, int out_size, void* d_ws, size_t ws_size,
                              hipStream_t stream) {
  const float* Q = (const float*)d_in[0];
  const float* K = (const float*)d_in[1];
  const float* V = (const float*)d_in[2];
  float* out = (float*)d_out;

  int ksplit = 8, kshift = 3;
  while (ksplit > 1) {
    size_t need = (size_t)ksplit * SEQ * HD * 4
                + (size_t)ksplit * SEQ * 4
                + (size_t)SEQ * HD * 2 * 2;
    if (need <= ws_size) break;
    ksplit >>= 1; kshift--;
  }

  char* ws = (char*)d_ws;
  float* Opart = (float*)ws;
  float* Lpart = (float*)(ws + (size_t)ksplit * SEQ * HD * 4);
  bf16_t* Kb = (bf16_t*)(ws + (size_t)ksplit * SEQ * HD * 4 + (size_t)ksplit * SEQ * 4);
  bf16_t* VT = Kb + (size_t)SEQ * HD;

  const int nit = SEQ / (ksplit * BN);

  prep_kernel<<<768, 256, 0, stream>>>(K, V, Kb, VT);
  fattn_kernel<<<NQT * ksplit, THREADS, 0, stream>>>(Q, Kb, VT, Opart, Lpart, kshift, nit);
  combine_kernel<<<SEQ / 8, 256, 0, stream>>>(Opart, Lpart, out, ksplit);
}